// Round 1
// baseline (2249.602 us; speedup 1.0000x reference)
//
#include <hip/hip_runtime.h>
#include <hip/hip_bf16.h>
#include <math.h>

#define B_  4
#define C_  768
#define T_  1000
#define SP_ 64        // 8*8 spatial
#define HEADS_ 12
#define DH_ 64        // head dim
#define WSZ_ 16
#define NWIN_ 63      // Tpad=1008 / 16
#define BT_ 4000      // B*T tokens

// ---------------------------------------------------------------------------
// K1: spatial mean with LDS transpose.  s[b,t,c] = mean_sp x[b,c,t,sp]
// grid: (16 t-tiles of 64, C/16=48, B), block 256
// ---------------------------------------------------------------------------
__global__ __launch_bounds__(256) void mean_kernel(const float* __restrict__ x,
                                                   float* __restrict__ s) {
    int b = blockIdx.z, c0 = blockIdx.y * 16, t0 = blockIdx.x * 64;
    __shared__ float tile[16][65];   // [cc][t_local], pad to break bank conflicts
    int tid = threadIdx.x;
    int tl = tid >> 2;      // 0..63 : t within tile
    int j  = tid & 3;       // 4 threads per (c,t) row
    int t = t0 + tl;
    for (int cc = 0; cc < 16; ++cc) {
        float sum = 0.f;
        if (t < T_) {
            const float4* p4 = (const float4*)(x + ((size_t)((b * C_ + c0 + cc) * T_) + t) * SP_);
            #pragma unroll
            for (int q = 0; q < 4; ++q) {
                float4 v = p4[j * 4 + q];
                sum += v.x + v.y + v.z + v.w;
            }
        }
        sum += __shfl_xor(sum, 1);
        sum += __shfl_xor(sum, 2);
        if (j == 0) tile[cc][tl] = sum;
    }
    __syncthreads();
    #pragma unroll
    for (int p = 0; p < 4; ++p) {
        int idx = p * 256 + tid;
        int tl2 = idx >> 4, cc = idx & 15;
        int tt = t0 + tl2;
        if (tt < T_)
            s[((size_t)b * T_ + tt) * C_ + c0 + cc] = tile[cc][tl2] * (1.f / 64.f);
    }
}

// ---------------------------------------------------------------------------
// K2: LayerNorm over C per token, in place.  grid: 4000 rows, block 256
// ---------------------------------------------------------------------------
__global__ __launch_bounds__(256) void ln_kernel(float* __restrict__ s,
                                                 const float* __restrict__ g,
                                                 const float* __restrict__ bb) {
    int row = blockIdx.x;
    float* p = s + (size_t)row * C_;
    int tid = threadIdx.x;
    float v[3];
    float sum = 0.f, sq = 0.f;
    #pragma unroll
    for (int i = 0; i < 3; ++i) {
        v[i] = p[tid + i * 256];
        sum += v[i];
        sq  += v[i] * v[i];
    }
    #pragma unroll
    for (int o = 1; o < 64; o <<= 1) {
        sum += __shfl_xor(sum, o);
        sq  += __shfl_xor(sq, o);
    }
    __shared__ float red[8];
    int wid = tid >> 6;
    if ((tid & 63) == 0) { red[wid] = sum; red[wid + 4] = sq; }
    __syncthreads();
    sum = red[0] + red[1] + red[2] + red[3];
    sq  = red[4] + red[5] + red[6] + red[7];
    float mu  = sum * (1.f / C_);
    float var = sq * (1.f / C_) - mu * mu;
    float rstd = rsqrtf(var + 1e-5f);
    #pragma unroll
    for (int i = 0; i < 3; ++i) {
        int c = tid + i * 256;
        p[c] = (v[i] - mu) * rstd * g[c] + bb[c];
    }
}

// ---------------------------------------------------------------------------
// K3/5/6/7: fp32 GEMM  out[M,N] = A[M,K] @ W[K,N] + bias  (opt GELU, opt +res)
// 64x64 tile, BK=16, 256 threads, 4x4 per thread
// ---------------------------------------------------------------------------
template <bool GELU, bool RES>
__global__ __launch_bounds__(256) void gemm_kernel(const float* __restrict__ A,
                                                   const float* __restrict__ W,
                                                   const float* __restrict__ bias,
                                                   const float* __restrict__ res,
                                                   float* __restrict__ out,
                                                   int M, int N, int K) {
    __shared__ float As[16][68];   // [k][m], padded: 16B-aligned float4 rows, no 4-way bank conflict
    __shared__ float Bs[16][64];   // [k][n]
    int tid = threadIdx.x;
    int n0 = blockIdx.x * 64, m0 = blockIdx.y * 64;
    int tx = tid & 15, ty = tid >> 4;
    int ar = tid >> 2;           // A tile row 0..63
    int ak = (tid & 3) * 4;      // A tile k offset
    int bk = tid >> 4;           // B tile k 0..15
    int bn = (tid & 15) * 4;     // B tile n offset
    bool arow_ok = (m0 + ar) < M;
    const float* Aptr = A + (size_t)(m0 + ar) * K + ak;
    float acc[4][4] = {};
    for (int k0 = 0; k0 < K; k0 += 16) {
        float4 av = arow_ok ? *(const float4*)(Aptr + k0) : float4{0.f, 0.f, 0.f, 0.f};
        float4 bv = *(const float4*)(W + (size_t)(k0 + bk) * N + n0 + bn);
        As[ak + 0][ar] = av.x;
        As[ak + 1][ar] = av.y;
        As[ak + 2][ar] = av.z;
        As[ak + 3][ar] = av.w;
        *(float4*)&Bs[bk][bn] = bv;
        __syncthreads();
        #pragma unroll
        for (int k = 0; k < 16; ++k) {
            float4 a4 = *(const float4*)&As[k][ty * 4];
            float4 b4 = *(const float4*)&Bs[k][tx * 4];
            acc[0][0] += a4.x * b4.x; acc[0][1] += a4.x * b4.y; acc[0][2] += a4.x * b4.z; acc[0][3] += a4.x * b4.w;
            acc[1][0] += a4.y * b4.x; acc[1][1] += a4.y * b4.y; acc[1][2] += a4.y * b4.z; acc[1][3] += a4.y * b4.w;
            acc[2][0] += a4.z * b4.x; acc[2][1] += a4.z * b4.y; acc[2][2] += a4.z * b4.z; acc[2][3] += a4.z * b4.w;
            acc[3][0] += a4.w * b4.x; acc[3][1] += a4.w * b4.y; acc[3][2] += a4.w * b4.z; acc[3][3] += a4.w * b4.w;
        }
        __syncthreads();
    }
    #pragma unroll
    for (int i = 0; i < 4; ++i) {
        int m = m0 + ty * 4 + i;
        if (m >= M) continue;
        #pragma unroll
        for (int jj = 0; jj < 4; ++jj) {
            int n = n0 + tx * 4 + jj;
            float v = acc[i][jj] + bias[n];
            if (GELU) v = 0.5f * v * (1.f + erff(v * 0.70710678118654752f));
            if (RES)  v += res[(size_t)m * N + n];
            out[(size_t)m * N + n] = v;
        }
    }
}

// ---------------------------------------------------------------------------
// K4: windowed attention, one wave per (b, head, window)
// grid (NWIN, HEADS, B), block 64
// ---------------------------------------------------------------------------
__global__ __launch_bounds__(64) void attn_kernel(const float* __restrict__ qkv,
                                                  const float* __restrict__ tau,
                                                  float* __restrict__ out) {
    int n = blockIdx.x, h = blockIdx.y, b = blockIdx.z;
    int lane = threadIdx.x;
    __shared__ float qs[16][65], ks[16][65], vs[16][65];
    __shared__ float as_[16][17];
    __shared__ float nq[16], nk[16];
    int t0 = n * WSZ_;
    // load window (zero-pad t >= T) — padded keys give logit 0 (participate in softmax)
    for (int r = 0; r < 16; ++r) {
        int t = t0 + r;
        float qv = 0.f, kv = 0.f, vv = 0.f;
        if (t < T_) {
            const float* base = qkv + (size_t)(b * T_ + t) * (3 * C_) + h * DH_ + lane;
            qv = base[0];
            kv = base[C_];
            vv = base[2 * C_];
        }
        qs[r][lane] = qv; ks[r][lane] = kv; vs[r][lane] = vv;
    }
    __syncthreads();
    if (lane < 32) {
        int r = lane & 15;
        const float(*m)[65] = (lane < 16) ? qs : ks;
        float sum = 0.f;
        for (int d = 0; d < 64; ++d) { float u = m[r][d]; sum += u * u; }
        float nn = fmaxf(sqrtf(sum), 1e-12f);
        if (lane < 16) nq[r] = nn; else nk[r] = nn;
    }
    __syncthreads();
    int w = lane & 15, sg = lane >> 4;
    float itau = 1.f / (tau[h] + 1e-6f);
    float lg[4];
    #pragma unroll
    for (int k2 = 0; k2 < 4; ++k2) {
        int sIdx = sg * 4 + k2;
        float acc = 0.f;
        for (int d = 0; d < 64; ++d) acc += qs[w][d] * ks[sIdx][d];
        lg[k2] = acc / (nq[w] * nk[sIdx]) * itau;
    }
    float mx = fmaxf(fmaxf(lg[0], lg[1]), fmaxf(lg[2], lg[3]));
    mx = fmaxf(mx, __shfl_xor(mx, 16));
    mx = fmaxf(mx, __shfl_xor(mx, 32));
    float e[4], ssum = 0.f;
    #pragma unroll
    for (int k2 = 0; k2 < 4; ++k2) { e[k2] = expf(lg[k2] - mx); ssum += e[k2]; }
    ssum += __shfl_xor(ssum, 16);
    ssum += __shfl_xor(ssum, 32);
    float inv = 1.f / ssum;
    #pragma unroll
    for (int k2 = 0; k2 < 4; ++k2) as_[w][sg * 4 + k2] = e[k2] * inv;
    __syncthreads();
    // out[w][dd], dd = lane
    for (int w2 = 0; w2 < 16; ++w2) {
        int t = t0 + w2;
        if (t >= T_) break;
        float acc = 0.f;
        #pragma unroll
        for (int s2 = 0; s2 < 16; ++s2) acc += as_[w2][s2] * vs[s2][lane];
        out[(size_t)(b * T_ + t) * C_ + h * DH_ + lane] = acc;
    }
}

// ---------------------------------------------------------------------------
// K8: result[b,c,t,i,j] = x + 0.5*z[b,t,c]
// each block: 16 (b,c,t) rows x 16 float4
// ---------------------------------------------------------------------------
__global__ __launch_bounds__(256) void final_add(const float* __restrict__ x,
                                                 const float* __restrict__ z,
                                                 float* __restrict__ out) {
    int tid = threadIdx.x;
    int bct = blockIdx.x * 16 + (tid >> 4);
    int q = tid & 15;
    int t = bct % T_;
    int bc = bct / T_;
    int c = bc % C_;
    int b = bc / C_;
    float zv = z[((size_t)b * T_ + t) * C_ + c] * 0.5f;
    size_t gi = (size_t)bct * 16 + q;
    float4 xv = ((const float4*)x)[gi];
    float4 o = {xv.x + zv, xv.y + zv, xv.z + zv, xv.w + zv};
    ((float4*)out)[gi] = o;
}

// ---------------------------------------------------------------------------
extern "C" void kernel_launch(void* const* d_in, const int* in_sizes, int n_in,
                              void* d_out, int out_size, void* d_ws, size_t ws_size,
                              hipStream_t stream) {
    const float* x      = (const float*)d_in[0];
    const float* ln_g   = (const float*)d_in[1];
    const float* ln_b   = (const float*)d_in[2];
    const float* tau    = (const float*)d_in[3];
    const float* w_qkv  = (const float*)d_in[4];
    const float* b_qkv  = (const float*)d_in[5];
    const float* w_proj = (const float*)d_in[6];
    const float* b_proj = (const float*)d_in[7];
    const float* w_mlp1 = (const float*)d_in[8];
    const float* b_mlp1 = (const float*)d_in[9];
    const float* w_mlp2 = (const float*)d_in[10];
    const float* b_mlp2 = (const float*)d_in[11];
    float* out = (float*)d_out;
    float* ws  = (float*)d_ws;

    // workspace layout (floats):
    float* s      = ws;              // [0, 3.072M)   s / s_ln ; later reused as z
    float* qkv    = ws + 3072000;    // [3.072M, 12.288M)
    float* attn   = ws + 12288000;   // [12.288M, 15.36M)
    float* y      = ws + 15360000;   // [15.36M, 18.432M)
    float* hidden = ws + 3072000;    // reuses qkv+attn region, 12.288M floats
    float* z      = ws;              // reuses s

    // 1. spatial mean -> s(B,T,C)
    mean_kernel<<<dim3(16, 48, B_), 256, 0, stream>>>(x, s);
    // 2. layernorm in place
    ln_kernel<<<BT_, 256, 0, stream>>>(s, ln_g, ln_b);
    // 3. qkv = s @ w_qkv + b_qkv   (4000 x 2304)
    gemm_kernel<false, false><<<dim3(36, 63), 256, 0, stream>>>(
        s, w_qkv, b_qkv, nullptr, qkv, BT_, 3 * C_, C_);
    // 4. windowed attention -> attn(B,T,C)
    attn_kernel<<<dim3(NWIN_, HEADS_, B_), 64, 0, stream>>>(qkv, tau, attn);
    // 5. y = attn @ w_proj + b_proj
    gemm_kernel<false, false><<<dim3(12, 63), 256, 0, stream>>>(
        attn, w_proj, b_proj, nullptr, y, BT_, C_, C_);
    // 6. hidden = gelu(y @ w_mlp1 + b_mlp1)
    gemm_kernel<true, false><<<dim3(48, 63), 256, 0, stream>>>(
        y, w_mlp1, b_mlp1, nullptr, hidden, BT_, 4 * C_, C_);
    // 7. z = y + hidden @ w_mlp2 + b_mlp2
    gemm_kernel<false, true><<<dim3(12, 63), 256, 0, stream>>>(
        hidden, w_mlp2, b_mlp2, y, z, BT_, C_, 4 * C_);
    // 8. out = x + 0.5 * z broadcast over spatial
    final_add<<<192000, 256, 0, stream>>>(x, z, out);
}